// Round 10
// baseline (144.755 us; speedup 1.0000x reference)
//
#include <hip/hip_runtime.h>
#include <cstdint>
#include <cstddef>

typedef __attribute__((ext_vector_type(8))) short short8;
typedef __attribute__((ext_vector_type(4))) float f32x4;
typedef __attribute__((ext_vector_type(2))) float f32x2;

#define MFMA16(a,b,c) __builtin_amdgcn_mfma_f32_16x16x32_bf16((a),(b),(c),0,0,0)
// LDS-only barrier: deliberately NO vmcnt drain (stores stay in flight)
#define BAR() asm volatile("s_waitcnt lgkmcnt(0)\n\ts_barrier" ::: "memory")

static __device__ __forceinline__ unsigned short f2bf(float f) {
  union { float f; unsigned u; } v; v.f = f;
  unsigned r = v.u + 0x7fffu + ((v.u >> 16) & 1u);
  return (unsigned short)(r >> 16);
}
static __device__ __forceinline__ float bf2f(unsigned short h) {
  union { unsigned u; float f; } v; v.u = ((unsigned)h) << 16;
  return v.f;
}

// ---------------- K0: weights f32 -> bf16 ----------------
__global__ __launch_bounds__(256) void k_wcvt(const float* __restrict__ w_val,
                                              const float* __restrict__ w_red,
                                              unsigned short* __restrict__ wv,
                                              unsigned short* __restrict__ wr) {
  int i = blockIdx.x * 256 + threadIdx.x;
  if (i < 65536) wv[i] = f2bf(w_val[i]);
  int j = i - 65536;
  if (j >= 0 && j < 8192) wr[j] = f2bf(w_red[j]);
}

// ---------------- K1: fused transpose + A/sq + val (p-tile 32, 2 WG/CU) ----------------
__global__ __launch_bounds__(512) void k_prep(const float* __restrict__ feat,
                                              const unsigned short* __restrict__ wv,
                                              const unsigned short* __restrict__ wr,
                                              const float* __restrict__ b_red,
                                              const float* __restrict__ b_val,
                                              unsigned short* __restrict__ A,
                                              float* __restrict__ sq,
                                              unsigned short* __restrict__ val) {
  __shared__ unsigned short smT[32][264];
  __shared__ float sqp[2][32];
  const int t = threadIdx.x, w = t >> 6, lane = t & 63, a = lane & 15, g = lane >> 4;
  const int b = blockIdx.y, p0 = blockIdx.x * 32;
  const float* fb = feat + (size_t)b * 256 * 4096;
  {
    const int p = t & 31, cg = t >> 5;
#pragma unroll
    for (int it = 0; it < 4; ++it) {
      int c0 = cg * 4 + it * 64;
      const float* src = fb + (size_t)c0 * 4096 + p0 + p;
      unsigned short u0 = f2bf(src[0]);
      unsigned short u1 = f2bf(src[4096]);
      unsigned short u2 = f2bf(src[8192]);
      unsigned short u3 = f2bf(src[12288]);
      uint2 pk;
      pk.x = u0 | ((unsigned)u1 << 16);
      pk.y = u2 | ((unsigned)u3 << 16);
      *(uint2*)&smT[p][c0] = pk;
    }
  }
  __syncthreads();

  f32x4 accv[2][2] = {};
  const int rs = w & 1, rms = (w >> 1) & 1;
  f32x4 accr = {0, 0, 0, 0};
#pragma unroll
  for (int kk = 0; kk < 8; ++kk) {
    short8 bfr[2];
#pragma unroll
    for (int ms = 0; ms < 2; ++ms)
      bfr[ms] = *(const short8*)&smT[ms * 16 + a][kk * 32 + g * 8];
#pragma unroll
    for (int s = 0; s < 2; ++s) {
      short8 af = *(const short8*)&wv[(w * 32 + s * 16 + a) * 256 + kk * 32 + g * 8];
#pragma unroll
      for (int ms = 0; ms < 2; ++ms)
        accv[s][ms] = MFMA16(af, bfr[ms], accv[s][ms]);
    }
    if (w < 4) {
      short8 wrf = *(const short8*)&wr[(rs * 16 + a) * 256 + kk * 32 + g * 8];
      accr = MFMA16(bfr[rms], wrf, accr);
    }
  }
#pragma unroll
  for (int s = 0; s < 2; ++s) {
    f32x4 bv = *(const f32x4*)&b_val[w * 32 + s * 16 + g * 4];
#pragma unroll
    for (int ms = 0; ms < 2; ++ms) {
#pragma unroll
      for (int r = 0; r < 4; ++r) {
        float v = accv[s][ms][r] + bv[r];
        v = v > 0.f ? v : 0.f;
        int o = w * 32 + s * 16 + g * 4 + r;
        val[((size_t)(b * 256 + o)) * 4096 + p0 + ms * 16 + a] = f2bf(v);
      }
    }
  }
  if (w < 4) {
    float bias = b_red[rs * 16 + a];
    float rsum[4];
    unsigned short* Ab = A + ((size_t)b * 4096 + p0 + rms * 16) * 32;
#pragma unroll
    for (int r = 0; r < 4; ++r) {
      float v = accr[r] + bias;
      v = v > 0.f ? v : 0.f;
      unsigned short h = f2bf(v);
      Ab[(g * 4 + r) * 32 + rs * 16 + a] = h;
      float vb = bf2f(h);
      rsum[r] = vb * vb;
    }
#pragma unroll
    for (int off = 1; off < 16; off <<= 1) {
#pragma unroll
      for (int r = 0; r < 4; ++r) rsum[r] += __shfl_xor(rsum[r], off, 64);
    }
    if (a == 0) {
#pragma unroll
      for (int r = 0; r < 4; ++r) sqp[rs][rms * 16 + g * 4 + r] = rsum[r];
    }
  }
  __syncthreads();
  if (t < 32) sq[(size_t)b * 4096 + p0 + t] = sqp[0][t] + sqp[1][t];
}

// mask subtile: S = A_n . A_m^T, mask = sigmoid(exp(-D)) packed to 2x2 bf16
static __device__ __forceinline__ uint2 mask_tile(const unsigned short* __restrict__ Ab,
                                                  const float* __restrict__ sqb,
                                                  int nbase, int ns, int a, int g,
                                                  short8 am, float sqm) {
  const f32x4 zero = {0, 0, 0, 0};
  short8 an = *(const short8*)&Ab[(size_t)(nbase + ns * 16 + a) * 32 + g * 8];
  f32x4 sqn = *(const f32x4*)&sqb[nbase + ns * 16 + g * 4];
  f32x4 sfr = MFMA16(an, am, zero);
  unsigned short h[4];
#pragma unroll
  for (int r = 0; r < 4; ++r) {
    float u = __expf(fmaf(2.f, sfr[r], -(sqn[r] + sqm)));  // exp(-D) in (0,1]
    float u2 = u * u;
    float pa = fmaf(u2, 2.0833333e-3f, -2.0833333e-2f);
    float pb = fmaf(u2, pa, 0.25f);
    h[r] = f2bf(fmaf(u, pb, 0.5f));  // sigmoid poly, |err|<=2.2e-4
  }
  uint2 pk;
  pk.x = h[0] | ((unsigned)h[1] << 16);
  pk.y = h[2] | ((unsigned)h[3] << 16);
  return pk;
}

// ---------------- K2: fused mask + (val @ mask) + residual, ROLE-SPECIALIZED ----------------
// 256 WGs (64 m-tiles of 64 x 4 b), 1024 thr (16 waves), 1 WG/CU.
//  waves 0-7  GEMM : val prefetch (1-step reg dbuf) + ldsT reads + 16 MFMA/step.
//  waves 8-11 S    : A/sq loads + 4 MFMA + exp -> bf16 tile tt+1 into ldsT[buf^1].
//  waves 12-15 STORE: read ldsT[buf], widen bf16->f32, NORMAL cached stores
//                     (512B contiguous/inst, full-line -> no RFO; L2 absorbs and
//                     drains to HBM asynchronously — the fill-kernel path).
// One lgkm-only barrier per step (no vmcnt drain anywhere in the loop).
__global__ __launch_bounds__(1024) void k_fused(const unsigned short* __restrict__ A,
                                                const float* __restrict__ sq,
                                                const unsigned short* __restrict__ val,
                                                const float* __restrict__ feat,
                                                float* __restrict__ dout) {
  __shared__ unsigned short ldsT[2][64][72];  // bf16 [m][n] tiles, 9 x 16B row stride
  const int t = threadIdx.x, w = t >> 6, lane = t & 63, a = lane & 15, g = lane >> 4;
  // bijective XCD swizzle: 32 contiguous WGs per XCD; XCD pair {2b,2b+1} <-> batch b
  const int lin = blockIdx.x + (blockIdx.y << 6);
  const int swz = (lin & 7) * 32 + (lin >> 3);
  const int b = swz >> 6, m0 = (swz & 63) * 64;
  const unsigned short* Ab = A + (size_t)b * 4096 * 32;
  const float* sqb = sq + (size_t)b * 4096;
  float* maskout = dout + 4194304 + (size_t)b * 16777216;

  if (w < 8) {
    // ================= GEMM waves: c rows [32w, 32w+32) =================
    const unsigned short* vrow = val + ((size_t)(b * 256 + w * 32)) * 4096;
    f32x4 acc[2][4] = {};
    short8 vf_c[2][2], vf_n[2][2];
#pragma unroll
    for (int cs = 0; cs < 2; ++cs)
#pragma unroll
      for (int ks = 0; ks < 2; ++ks)
        vf_c[cs][ks] = *(const short8*)&vrow[(size_t)(cs * 16 + a) * 4096 + ks * 32 + g * 8];
    BAR();
    for (int tt = 0; tt < 64; ++tt) {
      const int n0 = tt * 64, buf = tt & 1;
      // prefetch val fragments for step tt+1 (hides L2 latency under MFMA)
      if (tt < 63) {
#pragma unroll
        for (int cs = 0; cs < 2; ++cs)
#pragma unroll
          for (int ks = 0; ks < 2; ++ks)
            vf_n[cs][ks] = *(const short8*)&vrow[(size_t)(cs * 16 + a) * 4096 + n0 + 64 + ks * 32 + g * 8];
      }
      short8 bfr[2][4];
#pragma unroll
      for (int ks = 0; ks < 2; ++ks)
#pragma unroll
        for (int ms = 0; ms < 4; ++ms)
          bfr[ks][ms] = *(const short8*)&ldsT[buf][ms * 16 + a][ks * 32 + g * 8];
#pragma unroll
      for (int ks = 0; ks < 2; ++ks)
#pragma unroll
        for (int cs = 0; cs < 2; ++cs)
#pragma unroll
          for (int ms = 0; ms < 4; ++ms)
            acc[cs][ms] = MFMA16(vf_c[cs][ks], bfr[ks][ms], acc[cs][ms]);
      BAR();
#pragma unroll
      for (int cs = 0; cs < 2; ++cs)
#pragma unroll
        for (int ks = 0; ks < 2; ++ks) vf_c[cs][ks] = vf_n[cs][ks];
    }
    // epilogue: out = acc + features (normal stores; nt read-once feat loads)
    const float* fb = feat + (size_t)b * 256 * 4096;
    float* ob = dout + (size_t)b * 256 * 4096;
#pragma unroll
    for (int cs = 0; cs < 2; ++cs) {
#pragma unroll
      for (int ms = 0; ms < 4; ++ms) {
#pragma unroll
        for (int r = 0; r < 4; ++r) {
          int c = w * 32 + cs * 16 + g * 4 + r;
          int m = m0 + ms * 16 + a;
          size_t idx = (size_t)c * 4096 + m;
          float fv = __builtin_nontemporal_load(&fb[idx]);
          ob[idx] = acc[cs][ms][r] + fv;
        }
      }
    }
  } else if (w < 12) {
    // ================= S waves: m-rows [16(w-8), 16(w-8)+16) =================
    const int msub = w - 8;
    const int mrow = m0 + msub * 16 + a;
    const short8 am = *(const short8*)&Ab[(size_t)mrow * 32 + g * 8];
    const float sqm = sqb[mrow];
    // prologue: tile 0 -> ldsT[0]
#pragma unroll
    for (int ns = 0; ns < 4; ++ns) {
      uint2 pk = mask_tile(Ab, sqb, 0, ns, a, g, am, sqm);
      *(uint2*)&ldsT[0][msub * 16 + a][ns * 16 + g * 4] = pk;
    }
    BAR();
    for (int tt = 0; tt < 64; ++tt) {
      if (tt < 63) {
        const int nn = (tt + 1) * 64, tb = (tt + 1) & 1;
#pragma unroll
        for (int ns = 0; ns < 4; ++ns) {
          uint2 pk = mask_tile(Ab, sqb, nn, ns, a, g, am, sqm);
          *(uint2*)&ldsT[tb][msub * 16 + a][ns * 16 + g * 4] = pk;
        }
      }
      BAR();
    }
  } else {
    // ================= STORE waves: m-rows [16(w-12), 16(w-12)+16) =================
    const int sw = w - 12;
    const int rr = lane >> 5, cc = (lane & 31) * 2;
    BAR();
    for (int tt = 0; tt < 64; ++tt) {
      const int n0 = tt * 64, buf = tt & 1;
#pragma unroll
      for (int j = 0; j < 8; ++j) {
        const int row = sw * 16 + j * 2 + rr;
        unsigned u = *(const unsigned*)&ldsT[buf][row][cc];
        f32x2 v;
        v[0] = bf2f((unsigned short)(u & 0xffff));
        v[1] = bf2f((unsigned short)(u >> 16));
        *(f32x2*)&maskout[(size_t)(m0 + row) * 4096 + n0 + cc] = v;  // NORMAL cached store
      }
      BAR();
    }
  }
}

extern "C" void kernel_launch(void* const* d_in, const int* in_sizes, int n_in,
                              void* d_out, int out_size, void* d_ws, size_t ws_size,
                              hipStream_t stream) {
  const float* feat  = (const float*)d_in[0];
  const float* w_red = (const float*)d_in[1];
  const float* b_red = (const float*)d_in[2];
  const float* w_val = (const float*)d_in[3];
  const float* b_val = (const float*)d_in[4];
  float* out = (float*)d_out;
  char* ws = (char*)d_ws;
  unsigned short* A   = (unsigned short*)ws;               // 1,048,576 B
  float*          sq  = (float*)        (ws + 1048576);    //    65,536 B
  unsigned short* wv  = (unsigned short*)(ws + 1114112);   //   131,072 B
  unsigned short* wr  = (unsigned short*)(ws + 1245184);   //    16,384 B
  unsigned short* val = (unsigned short*)(ws + 1261568);   // 8,388,608 B

  k_wcvt<<<dim3(288), 256, 0, stream>>>(w_val, w_red, wv, wr);
  k_prep<<<dim3(128, 4), 512, 0, stream>>>(feat, wv, wr, b_red, b_val, A, sq, val);
  k_fused<<<dim3(64, 4), 1024, 0, stream>>>(A, sq, val, feat, out);
}

// Round 11
// 136.773 us; speedup vs baseline: 1.0584x; 1.0584x over previous
//
#include <hip/hip_runtime.h>
#include <cstdint>
#include <cstddef>

typedef __attribute__((ext_vector_type(8))) short short8;
typedef __attribute__((ext_vector_type(4))) float f32x4;
typedef __attribute__((ext_vector_type(2))) float f32x2;

#define MFMA16(a,b,c) __builtin_amdgcn_mfma_f32_16x16x32_bf16((a),(b),(c),0,0,0)
// LDS-only barrier: deliberately NO vmcnt drain (stores stay in flight)
#define BAR() asm volatile("s_waitcnt lgkmcnt(0)\n\ts_barrier" ::: "memory")

static __device__ __forceinline__ unsigned short f2bf(float f) {
  union { float f; unsigned u; } v; v.f = f;
  unsigned r = v.u + 0x7fffu + ((v.u >> 16) & 1u);
  return (unsigned short)(r >> 16);
}
static __device__ __forceinline__ float bf2f(unsigned short h) {
  union { unsigned u; float f; } v; v.u = ((unsigned)h) << 16;
  return v.f;
}

// ---------------- K0: weights f32 -> bf16 ----------------
__global__ __launch_bounds__(256) void k_wcvt(const float* __restrict__ w_val,
                                              const float* __restrict__ w_red,
                                              unsigned short* __restrict__ wv,
                                              unsigned short* __restrict__ wr) {
  int i = blockIdx.x * 256 + threadIdx.x;
  if (i < 65536) wv[i] = f2bf(w_val[i]);
  int j = i - 65536;
  if (j >= 0 && j < 8192) wr[j] = f2bf(w_red[j]);
}

// ---------------- K1: fused transpose + A/sq + val (p-tile 32, 2 WG/CU) ----------------
__global__ __launch_bounds__(512) void k_prep(const float* __restrict__ feat,
                                              const unsigned short* __restrict__ wv,
                                              const unsigned short* __restrict__ wr,
                                              const float* __restrict__ b_red,
                                              const float* __restrict__ b_val,
                                              unsigned short* __restrict__ A,
                                              float* __restrict__ sq,
                                              unsigned short* __restrict__ val) {
  __shared__ unsigned short smT[32][264];
  __shared__ float sqp[2][32];
  const int t = threadIdx.x, w = t >> 6, lane = t & 63, a = lane & 15, g = lane >> 4;
  const int b = blockIdx.y, p0 = blockIdx.x * 32;
  const float* fb = feat + (size_t)b * 256 * 4096;
  {
    const int p = t & 31, cg = t >> 5;
#pragma unroll
    for (int it = 0; it < 4; ++it) {
      int c0 = cg * 4 + it * 64;
      const float* src = fb + (size_t)c0 * 4096 + p0 + p;
      unsigned short u0 = f2bf(src[0]);
      unsigned short u1 = f2bf(src[4096]);
      unsigned short u2 = f2bf(src[8192]);
      unsigned short u3 = f2bf(src[12288]);
      uint2 pk;
      pk.x = u0 | ((unsigned)u1 << 16);
      pk.y = u2 | ((unsigned)u3 << 16);
      *(uint2*)&smT[p][c0] = pk;
    }
  }
  __syncthreads();

  f32x4 accv[2][2] = {};
  const int rs = w & 1, rms = (w >> 1) & 1;
  f32x4 accr = {0, 0, 0, 0};
#pragma unroll
  for (int kk = 0; kk < 8; ++kk) {
    short8 bfr[2];
#pragma unroll
    for (int ms = 0; ms < 2; ++ms)
      bfr[ms] = *(const short8*)&smT[ms * 16 + a][kk * 32 + g * 8];
#pragma unroll
    for (int s = 0; s < 2; ++s) {
      short8 af = *(const short8*)&wv[(w * 32 + s * 16 + a) * 256 + kk * 32 + g * 8];
#pragma unroll
      for (int ms = 0; ms < 2; ++ms)
        accv[s][ms] = MFMA16(af, bfr[ms], accv[s][ms]);
    }
    if (w < 4) {
      short8 wrf = *(const short8*)&wr[(rs * 16 + a) * 256 + kk * 32 + g * 8];
      accr = MFMA16(bfr[rms], wrf, accr);
    }
  }
#pragma unroll
  for (int s = 0; s < 2; ++s) {
    f32x4 bv = *(const f32x4*)&b_val[w * 32 + s * 16 + g * 4];
#pragma unroll
    for (int ms = 0; ms < 2; ++ms) {
#pragma unroll
      for (int r = 0; r < 4; ++r) {
        float v = accv[s][ms][r] + bv[r];
        v = v > 0.f ? v : 0.f;
        int o = w * 32 + s * 16 + g * 4 + r;
        val[((size_t)(b * 256 + o)) * 4096 + p0 + ms * 16 + a] = f2bf(v);
      }
    }
  }
  if (w < 4) {
    float bias = b_red[rs * 16 + a];
    float rsum[4];
    unsigned short* Ab = A + ((size_t)b * 4096 + p0 + rms * 16) * 32;
#pragma unroll
    for (int r = 0; r < 4; ++r) {
      float v = accr[r] + bias;
      v = v > 0.f ? v : 0.f;
      unsigned short h = f2bf(v);
      Ab[(g * 4 + r) * 32 + rs * 16 + a] = h;
      float vb = bf2f(h);
      rsum[r] = vb * vb;
    }
#pragma unroll
    for (int off = 1; off < 16; off <<= 1) {
#pragma unroll
      for (int r = 0; r < 4; ++r) rsum[r] += __shfl_xor(rsum[r], off, 64);
    }
    if (a == 0) {
#pragma unroll
      for (int r = 0; r < 4; ++r) sqp[rs][rms * 16 + g * 4 + r] = rsum[r];
    }
  }
  __syncthreads();
  if (t < 32) sq[(size_t)b * 4096 + p0 + t] = sqp[0][t] + sqp[1][t];
}

// mask subtile: S = A_n . A_m^T, mask = sigmoid(exp(-D)) packed to 2x2 bf16
static __device__ __forceinline__ uint2 mask_tile(const unsigned short* __restrict__ Ab,
                                                  const float* __restrict__ sqb,
                                                  int nbase, int ns, int a, int g,
                                                  short8 am, float sqm) {
  const f32x4 zero = {0, 0, 0, 0};
  short8 an = *(const short8*)&Ab[(size_t)(nbase + ns * 16 + a) * 32 + g * 8];
  f32x4 sqn = *(const f32x4*)&sqb[nbase + ns * 16 + g * 4];
  f32x4 sfr = MFMA16(an, am, zero);
  unsigned short h[4];
#pragma unroll
  for (int r = 0; r < 4; ++r) {
    float u = __expf(fmaf(2.f, sfr[r], -(sqn[r] + sqm)));  // exp(-D) in (0,1]
    float u2 = u * u;
    float pa = fmaf(u2, 2.0833333e-3f, -2.0833333e-2f);
    float pb = fmaf(u2, pa, 0.25f);
    h[r] = f2bf(fmaf(u, pb, 0.5f));  // sigmoid poly, |err|<=2.2e-4
  }
  uint2 pk;
  pk.x = h[0] | ((unsigned)h[1] << 16);
  pk.y = h[2] | ((unsigned)h[3] << 16);
  return pk;
}

// ---------------- K2: fused mask + (val @ mask) + residual, ROLE-SPECIALIZED ----------------
// Identical to the r9 (127 us) config except ONE variable: store waves emit
// system-scope cached stores (sc0 sc1, no nt) instead of nontemporal. Theory:
// nt bypasses L2 AND the memory-side Infinity Cache -> quasi-synchronous HBM
// writes capped ~2.8 TB/s (= the whole kernel's critical path). sc0 sc1 must
// bypass the per-XCD L2 (no pollution) but lands in the MALL, which absorbs at
// near-fill rate (fills do 6.7 TB/s).
//  waves 0-7  GEMM : val loads + ldsT reads + 16 MFMA/step.
//  waves 8-11 S    : A/sq loads + 4 MFMA + exp -> bf16 tile tt+1 into ldsT.
//  waves 12-15 STORE: ldsT -> widen -> 512B-contiguous sc0sc1 stores; their
//                     vmcnt queue is never waited on.
__global__ __launch_bounds__(1024) void k_fused(const unsigned short* __restrict__ A,
                                                const float* __restrict__ sq,
                                                const unsigned short* __restrict__ val,
                                                const float* __restrict__ feat,
                                                float* __restrict__ dout) {
  __shared__ unsigned short ldsT[2][64][72];  // bf16 [m][n] tiles, 9 x 16B row stride
  const int t = threadIdx.x, w = t >> 6, lane = t & 63, a = lane & 15, g = lane >> 4;
  // bijective XCD swizzle: 32 contiguous WGs per XCD; XCD pair {2b,2b+1} <-> batch b
  const int lin = blockIdx.x + (blockIdx.y << 6);
  const int swz = (lin & 7) * 32 + (lin >> 3);
  const int b = swz >> 6, m0 = (swz & 63) * 64;
  const unsigned short* Ab = A + (size_t)b * 4096 * 32;
  const float* sqb = sq + (size_t)b * 4096;
  float* maskout = dout + 4194304 + (size_t)b * 16777216;

  if (w < 8) {
    // ================= GEMM waves: c rows [32w, 32w+32) =================
    const unsigned short* vrow = val + ((size_t)(b * 256 + w * 32)) * 4096;
    f32x4 acc[2][4] = {};
    BAR();
    for (int tt = 0; tt < 64; ++tt) {
      const int n0 = tt * 64, buf = tt & 1;
      short8 vf[2][2];
#pragma unroll
      for (int cs = 0; cs < 2; ++cs)
#pragma unroll
        for (int ks = 0; ks < 2; ++ks)
          vf[cs][ks] = *(const short8*)&vrow[(size_t)(cs * 16 + a) * 4096 + n0 + ks * 32 + g * 8];
      short8 bfr[2][4];
#pragma unroll
      for (int ks = 0; ks < 2; ++ks)
#pragma unroll
        for (int ms = 0; ms < 4; ++ms)
          bfr[ks][ms] = *(const short8*)&ldsT[buf][ms * 16 + a][ks * 32 + g * 8];
#pragma unroll
      for (int ks = 0; ks < 2; ++ks)
#pragma unroll
        for (int cs = 0; cs < 2; ++cs)
#pragma unroll
          for (int ms = 0; ms < 4; ++ms)
            acc[cs][ms] = MFMA16(vf[cs][ks], bfr[ks][ms], acc[cs][ms]);
      BAR();
    }
    // epilogue: out = acc + features
    const float* fb = feat + (size_t)b * 256 * 4096;
    float* ob = dout + (size_t)b * 256 * 4096;
#pragma unroll
    for (int cs = 0; cs < 2; ++cs) {
#pragma unroll
      for (int ms = 0; ms < 4; ++ms) {
#pragma unroll
        for (int r = 0; r < 4; ++r) {
          int c = w * 32 + cs * 16 + g * 4 + r;
          int m = m0 + ms * 16 + a;
          size_t idx = (size_t)c * 4096 + m;
          float fv = __builtin_nontemporal_load(&fb[idx]);
          __builtin_nontemporal_store(acc[cs][ms][r] + fv, &ob[idx]);
        }
      }
    }
  } else if (w < 12) {
    // ================= S waves: m-rows [16(w-8), 16(w-8)+16) =================
    const int msub = w - 8;
    const int mrow = m0 + msub * 16 + a;
    const short8 am = *(const short8*)&Ab[(size_t)mrow * 32 + g * 8];
    const float sqm = sqb[mrow];
    // prologue: tile 0 -> ldsT[0]
#pragma unroll
    for (int ns = 0; ns < 4; ++ns) {
      uint2 pk = mask_tile(Ab, sqb, 0, ns, a, g, am, sqm);
      *(uint2*)&ldsT[0][msub * 16 + a][ns * 16 + g * 4] = pk;
    }
    BAR();
    for (int tt = 0; tt < 64; ++tt) {
      if (tt < 63) {
        const int nn = (tt + 1) * 64, tb = (tt + 1) & 1;
#pragma unroll
        for (int ns = 0; ns < 4; ++ns) {
          uint2 pk = mask_tile(Ab, sqb, nn, ns, a, g, am, sqm);
          *(uint2*)&ldsT[tb][msub * 16 + a][ns * 16 + g * 4] = pk;
        }
      }
      BAR();
    }
  } else {
    // ================= STORE waves: m-rows [16(w-12), 16(w-12)+16) =================
    const int sw = w - 12;
    const int rr = lane >> 5, cc = (lane & 31) * 2;
    BAR();
    for (int tt = 0; tt < 64; ++tt) {
      const int n0 = tt * 64, buf = tt & 1;
#pragma unroll
      for (int j = 0; j < 8; ++j) {
        const int row = sw * 16 + j * 2 + rr;
        unsigned u = *(const unsigned*)&ldsT[buf][row][cc];
        f32x2 v;
        v[0] = bf2f((unsigned short)(u & 0xffff));
        v[1] = bf2f((unsigned short)(u >> 16));
        float* p = &maskout[(size_t)(m0 + row) * 4096 + n0 + cc];
        // system-scope cached store: bypass per-XCD L2, absorbed by MALL
        asm volatile("global_store_dwordx2 %0, %1, off sc0 sc1"
                     :: "v"(p), "v"(v) : "memory");
      }
      BAR();
    }
  }
}

extern "C" void kernel_launch(void* const* d_in, const int* in_sizes, int n_in,
                              void* d_out, int out_size, void* d_ws, size_t ws_size,
                              hipStream_t stream) {
  const float* feat  = (const float*)d_in[0];
  const float* w_red = (const float*)d_in[1];
  const float* b_red = (const float*)d_in[2];
  const float* w_val = (const float*)d_in[3];
  const float* b_val = (const float*)d_in[4];
  float* out = (float*)d_out;
  char* ws = (char*)d_ws;
  unsigned short* A   = (unsigned short*)ws;               // 1,048,576 B
  float*          sq  = (float*)        (ws + 1048576);    //    65,536 B
  unsigned short* wv  = (unsigned short*)(ws + 1114112);   //   131,072 B
  unsigned short* wr  = (unsigned short*)(ws + 1245184);   //    16,384 B
  unsigned short* val = (unsigned short*)(ws + 1261568);   // 8,388,608 B

  k_wcvt<<<dim3(288), 256, 0, stream>>>(w_val, w_red, wv, wr);
  k_prep<<<dim3(128, 4), 512, 0, stream>>>(feat, wv, wr, b_red, b_val, A, sq, val);
  k_fused<<<dim3(64, 4), 1024, 0, stream>>>(A, sq, val, feat, out);
}

// Round 12
// 133.817 us; speedup vs baseline: 1.0817x; 1.0221x over previous
//
#include <hip/hip_runtime.h>
#include <cstdint>
#include <cstddef>

typedef __attribute__((ext_vector_type(8))) short short8;
typedef __attribute__((ext_vector_type(4))) float f32x4;
typedef __attribute__((ext_vector_type(2))) float f32x2;

#define MFMA16(a,b,c) __builtin_amdgcn_mfma_f32_16x16x32_bf16((a),(b),(c),0,0,0)
// LDS-only barrier: deliberately NO vmcnt drain (stores stay in flight)
#define BAR() asm volatile("s_waitcnt lgkmcnt(0)\n\ts_barrier" ::: "memory")

static __device__ __forceinline__ unsigned short f2bf(float f) {
  union { float f; unsigned u; } v; v.f = f;
  unsigned r = v.u + 0x7fffu + ((v.u >> 16) & 1u);
  return (unsigned short)(r >> 16);
}
static __device__ __forceinline__ float bf2f(unsigned short h) {
  union { unsigned u; float f; } v; v.u = ((unsigned)h) << 16;
  return v.f;
}

// ---------------- K0: weights f32 -> bf16 ----------------
__global__ __launch_bounds__(256) void k_wcvt(const float* __restrict__ w_val,
                                              const float* __restrict__ w_red,
                                              unsigned short* __restrict__ wv,
                                              unsigned short* __restrict__ wr) {
  int i = blockIdx.x * 256 + threadIdx.x;
  if (i < 65536) wv[i] = f2bf(w_val[i]);
  int j = i - 65536;
  if (j >= 0 && j < 8192) wr[j] = f2bf(w_red[j]);
}

// ---------------- K1: fused transpose + A/sq + val (p-tile 32, 2 WG/CU) ----------------
__global__ __launch_bounds__(512) void k_prep(const float* __restrict__ feat,
                                              const unsigned short* __restrict__ wv,
                                              const unsigned short* __restrict__ wr,
                                              const float* __restrict__ b_red,
                                              const float* __restrict__ b_val,
                                              unsigned short* __restrict__ A,
                                              float* __restrict__ sq,
                                              unsigned short* __restrict__ val) {
  __shared__ unsigned short smT[32][264];
  __shared__ float sqp[2][32];
  const int t = threadIdx.x, w = t >> 6, lane = t & 63, a = lane & 15, g = lane >> 4;
  const int b = blockIdx.y, p0 = blockIdx.x * 32;
  const float* fb = feat + (size_t)b * 256 * 4096;
  {
    const int p = t & 31, cg = t >> 5;
#pragma unroll
    for (int it = 0; it < 4; ++it) {
      int c0 = cg * 4 + it * 64;
      const float* src = fb + (size_t)c0 * 4096 + p0 + p;
      unsigned short u0 = f2bf(src[0]);
      unsigned short u1 = f2bf(src[4096]);
      unsigned short u2 = f2bf(src[8192]);
      unsigned short u3 = f2bf(src[12288]);
      uint2 pk;
      pk.x = u0 | ((unsigned)u1 << 16);
      pk.y = u2 | ((unsigned)u3 << 16);
      *(uint2*)&smT[p][c0] = pk;
    }
  }
  __syncthreads();

  f32x4 accv[2][2] = {};
  const int rs = w & 1, rms = (w >> 1) & 1;
  f32x4 accr = {0, 0, 0, 0};
#pragma unroll
  for (int kk = 0; kk < 8; ++kk) {
    short8 bfr[2];
#pragma unroll
    for (int ms = 0; ms < 2; ++ms)
      bfr[ms] = *(const short8*)&smT[ms * 16 + a][kk * 32 + g * 8];
#pragma unroll
    for (int s = 0; s < 2; ++s) {
      short8 af = *(const short8*)&wv[(w * 32 + s * 16 + a) * 256 + kk * 32 + g * 8];
#pragma unroll
      for (int ms = 0; ms < 2; ++ms)
        accv[s][ms] = MFMA16(af, bfr[ms], accv[s][ms]);
    }
    if (w < 4) {
      short8 wrf = *(const short8*)&wr[(rs * 16 + a) * 256 + kk * 32 + g * 8];
      accr = MFMA16(bfr[rms], wrf, accr);
    }
  }
#pragma unroll
  for (int s = 0; s < 2; ++s) {
    f32x4 bv = *(const f32x4*)&b_val[w * 32 + s * 16 + g * 4];
#pragma unroll
    for (int ms = 0; ms < 2; ++ms) {
#pragma unroll
      for (int r = 0; r < 4; ++r) {
        float v = accv[s][ms][r] + bv[r];
        v = v > 0.f ? v : 0.f;
        int o = w * 32 + s * 16 + g * 4 + r;
        val[((size_t)(b * 256 + o)) * 4096 + p0 + ms * 16 + a] = f2bf(v);
      }
    }
  }
  if (w < 4) {
    float bias = b_red[rs * 16 + a];
    float rsum[4];
    unsigned short* Ab = A + ((size_t)b * 4096 + p0 + rms * 16) * 32;
#pragma unroll
    for (int r = 0; r < 4; ++r) {
      float v = accr[r] + bias;
      v = v > 0.f ? v : 0.f;
      unsigned short h = f2bf(v);
      Ab[(g * 4 + r) * 32 + rs * 16 + a] = h;
      float vb = bf2f(h);
      rsum[r] = vb * vb;
    }
#pragma unroll
    for (int off = 1; off < 16; off <<= 1) {
#pragma unroll
      for (int r = 0; r < 4; ++r) rsum[r] += __shfl_xor(rsum[r], off, 64);
    }
    if (a == 0) {
#pragma unroll
      for (int r = 0; r < 4; ++r) sqp[rs][rms * 16 + g * 4 + r] = rsum[r];
    }
  }
  __syncthreads();
  if (t < 32) sq[(size_t)b * 4096 + p0 + t] = sqp[0][t] + sqp[1][t];
}

// mask subtile: S = A_n . A_m^T, mask = sigmoid(exp(-D)) packed to 2x2 bf16
static __device__ __forceinline__ uint2 mask_tile(const unsigned short* __restrict__ Ab,
                                                  const float* __restrict__ sqb,
                                                  int nbase, int ns, int a, int g,
                                                  short8 am, float sqm) {
  const f32x4 zero = {0, 0, 0, 0};
  short8 an = *(const short8*)&Ab[(size_t)(nbase + ns * 16 + a) * 32 + g * 8];
  f32x4 sqn = *(const f32x4*)&sqb[nbase + ns * 16 + g * 4];
  f32x4 sfr = MFMA16(an, am, zero);
  unsigned short h[4];
#pragma unroll
  for (int r = 0; r < 4; ++r) {
    float u = __expf(fmaf(2.f, sfr[r], -(sqn[r] + sqm)));  // exp(-D) in (0,1]
    float u2 = u * u;
    float pa = fmaf(u2, 2.0833333e-3f, -2.0833333e-2f);
    float pb = fmaf(u2, pa, 0.25f);
    h[r] = f2bf(fmaf(u, pb, 0.5f));  // sigmoid poly, |err|<=2.2e-4
  }
  uint2 pk;
  pk.x = h[0] | ((unsigned)h[1] << 16);
  pk.y = h[2] | ((unsigned)h[3] << 16);
  return pk;
}

// ---------------- K2: fused mask + (val @ mask) + residual, ROLE-SPECIALIZED ----------------
// r9 (127 us) config + ONE variable: store waves split 50/50 between the
// nontemporal path (HBM-direct) and the cached path (L2 writeback engine).
// If the two drain paths are independent, bandwidths add (~2.9 + ~2.5 TB/s);
// cached half covers full 128B lines (256B chunks) so no RFO, and pollution
// is halved vs r10.
//  waves 0-7  GEMM : val loads + ldsT reads + 16 MFMA/step.
//  waves 8-11 S    : A/sq loads + 4 MFMA + exp -> bf16 tile tt+1 into ldsT.
//  waves 12-15 STORE: ldsT -> widen -> 256B rows; sw even = nt, sw odd = cached.
// One lgkm-only barrier per step (no vmcnt drain anywhere in the loop).
__global__ __launch_bounds__(1024) void k_fused(const unsigned short* __restrict__ A,
                                                const float* __restrict__ sq,
                                                const unsigned short* __restrict__ val,
                                                const float* __restrict__ feat,
                                                float* __restrict__ dout) {
  __shared__ unsigned short ldsT[2][64][72];  // bf16 [m][n] tiles, 9 x 16B row stride
  const int t = threadIdx.x, w = t >> 6, lane = t & 63, a = lane & 15, g = lane >> 4;
  // bijective XCD swizzle: 32 contiguous WGs per XCD; XCD pair {2b,2b+1} <-> batch b
  const int lin = blockIdx.x + (blockIdx.y << 6);
  const int swz = (lin & 7) * 32 + (lin >> 3);
  const int b = swz >> 6, m0 = (swz & 63) * 64;
  const unsigned short* Ab = A + (size_t)b * 4096 * 32;
  const float* sqb = sq + (size_t)b * 4096;
  float* maskout = dout + 4194304 + (size_t)b * 16777216;

  if (w < 8) {
    // ================= GEMM waves: c rows [32w, 32w+32) =================
    const unsigned short* vrow = val + ((size_t)(b * 256 + w * 32)) * 4096;
    f32x4 acc[2][4] = {};
    BAR();
    for (int tt = 0; tt < 64; ++tt) {
      const int n0 = tt * 64, buf = tt & 1;
      short8 vf[2][2];
#pragma unroll
      for (int cs = 0; cs < 2; ++cs)
#pragma unroll
        for (int ks = 0; ks < 2; ++ks)
          vf[cs][ks] = *(const short8*)&vrow[(size_t)(cs * 16 + a) * 4096 + n0 + ks * 32 + g * 8];
      short8 bfr[2][4];
#pragma unroll
      for (int ks = 0; ks < 2; ++ks)
#pragma unroll
        for (int ms = 0; ms < 4; ++ms)
          bfr[ks][ms] = *(const short8*)&ldsT[buf][ms * 16 + a][ks * 32 + g * 8];
#pragma unroll
      for (int ks = 0; ks < 2; ++ks)
#pragma unroll
        for (int cs = 0; cs < 2; ++cs)
#pragma unroll
          for (int ms = 0; ms < 4; ++ms)
            acc[cs][ms] = MFMA16(vf[cs][ks], bfr[ks][ms], acc[cs][ms]);
      BAR();
    }
    // epilogue: out = acc + features
    const float* fb = feat + (size_t)b * 256 * 4096;
    float* ob = dout + (size_t)b * 256 * 4096;
#pragma unroll
    for (int cs = 0; cs < 2; ++cs) {
#pragma unroll
      for (int ms = 0; ms < 4; ++ms) {
#pragma unroll
        for (int r = 0; r < 4; ++r) {
          int c = w * 32 + cs * 16 + g * 4 + r;
          int m = m0 + ms * 16 + a;
          size_t idx = (size_t)c * 4096 + m;
          float fv = __builtin_nontemporal_load(&fb[idx]);
          __builtin_nontemporal_store(acc[cs][ms][r] + fv, &ob[idx]);
        }
      }
    }
  } else if (w < 12) {
    // ================= S waves: m-rows [16(w-8), 16(w-8)+16) =================
    const int msub = w - 8;
    const int mrow = m0 + msub * 16 + a;
    const short8 am = *(const short8*)&Ab[(size_t)mrow * 32 + g * 8];
    const float sqm = sqb[mrow];
    // prologue: tile 0 -> ldsT[0]
#pragma unroll
    for (int ns = 0; ns < 4; ++ns) {
      uint2 pk = mask_tile(Ab, sqb, 0, ns, a, g, am, sqm);
      *(uint2*)&ldsT[0][msub * 16 + a][ns * 16 + g * 4] = pk;
    }
    BAR();
    for (int tt = 0; tt < 64; ++tt) {
      if (tt < 63) {
        const int nn = (tt + 1) * 64, tb = (tt + 1) & 1;
#pragma unroll
        for (int ns = 0; ns < 4; ++ns) {
          uint2 pk = mask_tile(Ab, sqb, nn, ns, a, g, am, sqm);
          *(uint2*)&ldsT[tb][msub * 16 + a][ns * 16 + g * 4] = pk;
        }
      }
      BAR();
    }
  } else {
    // ================= STORE waves: m-rows [16(w-12), 16(w-12)+16) =================
    const int sw = w - 12;
    const bool use_nt = (sw & 1) == 0;  // waves 12,14 -> nt; 13,15 -> cached
    const int rr = lane >> 5, cc = (lane & 31) * 2;
    BAR();
    for (int tt = 0; tt < 64; ++tt) {
      const int n0 = tt * 64, buf = tt & 1;
#pragma unroll
      for (int j = 0; j < 8; ++j) {
        const int row = sw * 16 + j * 2 + rr;
        unsigned u = *(const unsigned*)&ldsT[buf][row][cc];
        f32x2 v;
        v[0] = bf2f((unsigned short)(u & 0xffff));
        v[1] = bf2f((unsigned short)(u >> 16));
        float* p = &maskout[(size_t)(m0 + row) * 4096 + n0 + cc];
        if (use_nt)
          __builtin_nontemporal_store(v, (f32x2*)p);  // HBM-direct queue
        else
          *(f32x2*)p = v;                             // L2 writeback engine
      }
      BAR();
    }
  }
}

extern "C" void kernel_launch(void* const* d_in, const int* in_sizes, int n_in,
                              void* d_out, int out_size, void* d_ws, size_t ws_size,
                              hipStream_t stream) {
  const float* feat  = (const float*)d_in[0];
  const float* w_red = (const float*)d_in[1];
  const float* b_red = (const float*)d_in[2];
  const float* w_val = (const float*)d_in[3];
  const float* b_val = (const float*)d_in[4];
  float* out = (float*)d_out;
  char* ws = (char*)d_ws;
  unsigned short* A   = (unsigned short*)ws;               // 1,048,576 B
  float*          sq  = (float*)        (ws + 1048576);    //    65,536 B
  unsigned short* wv  = (unsigned short*)(ws + 1114112);   //   131,072 B
  unsigned short* wr  = (unsigned short*)(ws + 1245184);   //    16,384 B
  unsigned short* val = (unsigned short*)(ws + 1261568);   // 8,388,608 B

  k_wcvt<<<dim3(288), 256, 0, stream>>>(w_val, w_red, wv, wr);
  k_prep<<<dim3(128, 4), 512, 0, stream>>>(feat, wv, wr, b_red, b_val, A, sq, val);
  k_fused<<<dim3(64, 4), 1024, 0, stream>>>(A, sq, val, feat, out);
}